// Round 7
// baseline (87.922 us; speedup 1.0000x reference)
//
#include <hip/hip_runtime.h>
#include <hip/hip_bf16.h>

// Problem constants (match reference)
#define PB 8          // batches
#define PS 2048       // sequence length
#define PN 4096       // spans per batch
#define PD 256        // feature dim
#define RCH 16        // rows per chunk (== MAX_W, so a span crosses <=1 boundary)
#define NRCH (PS / RCH)   // 128 chunks per batch
// MAX_W = 16: start in [0, S-16), width in [0,15]; span = rows start..end,
// n = end-start+1 in [1,16]. Since n <= 16, c1 = end>>4 <= (start>>4)+1.

typedef float vf4 __attribute__((ext_vector_type(4)));

// ---------------------------------------------------------------------------
// K1: build chunk-local prefix Q and suffix R. One block per (batch, chunk):
// 1024 blocks, zero cross-block dependencies (this is what makes the prefix
// idea cheap — R3 paid 3 kernel boundaries, R4 paid coherence stalls).
// Q[b,s,d] = sum seq[b, 16*(s/16) .. s, d]   (prefix within 16-row chunk)
// R[b,s,d] = sum seq[b, s .. 16*(s/16)+15, d] (suffix within chunk)
__global__ __launch_bounds__(256) void k_buildQR(const float* __restrict__ seq,
                                                 float* __restrict__ Q,
                                                 float* __restrict__ R) {
    const int b = blockIdx.x & 7;          // batch == XCD (round-robin)
    const int c = blockIdx.x >> 3;         // chunk 0..127
    const int d = threadIdx.x;             // column 0..255
    const size_t base = ((size_t)b * PS + (size_t)c * RCH) * PD + d;

    float x[RCH];
    #pragma unroll
    for (int i = 0; i < RCH; ++i) x[i] = seq[base + (size_t)i * PD];

    float q = 0.f;
    #pragma unroll
    for (int i = 0; i < RCH; ++i) { q += x[i]; Q[base + (size_t)i * PD] = q; }

    float r = 0.f;
    #pragma unroll
    for (int i = RCH - 1; i >= 0; --i) { r += x[i]; R[base + (size_t)i * PD] = r; }
}

// ---------------------------------------------------------------------------
// K2: gather. One wave per span; lane owns float4 [4*lane, 4*lane+4).
// <=2 row-reads per span (vs ~8.5 direct) — the gather is L1-BW-bound, so
// bytes-through-L1 is the lever (R2 vs R6: MLP restructure was neutral).
__global__ __launch_bounds__(256) void k_gather(const float* __restrict__ Q,
                                               const float* __restrict__ R,
                                               const int*   __restrict__ spans,
                                               float*       __restrict__ out) {
    const int b       = blockIdx.x & 7;            // batch == XCD
    const int blk     = blockIdx.x >> 3;
    const int span_ib = (blk << 2) | (threadIdx.x >> 6);
    const int span    = (b << 12) | span_ib;
    const int lane    = threadIdx.x & 63;

    const int2 se   = ((const int2*)spans)[span];  // broadcast load
    const int start = __builtin_amdgcn_readfirstlane(se.x);
    const int end   = __builtin_amdgcn_readfirstlane(se.y);
    const float inv = 1.0f / (float)(end - start + 1);

    const size_t rowoff = (size_t)b * PS * PD + (lane << 2);

    const vf4 a = *(const vf4*)(Q + rowoff + (size_t)end * PD);
    vf4 s;
    if ((start >> 4) != (end >> 4)) {
        // span crosses one chunk boundary: suffix of start's chunk + prefix of end's
        s = a + *(const vf4*)(R + rowoff + (size_t)start * PD);
    } else if (start & 15) {
        // same chunk, start not at chunk head: difference of prefixes
        s = a - *(const vf4*)(Q + rowoff + (size_t)(start - 1) * PD);
    } else {
        // same chunk, start at chunk head: prefix alone
        s = a;
    }
    const vf4 r = s * inv;

    // out is write-once: NT store keeps the 4 MiB/XCD Q+R slice L2-resident.
    __builtin_nontemporal_store(r, (vf4*)(out + (size_t)span * PD + (lane << 2)));
}

extern "C" void kernel_launch(void* const* d_in, const int* in_sizes, int n_in,
                              void* d_out, int out_size, void* d_ws, size_t ws_size,
                              hipStream_t stream) {
    const float* seq   = (const float*)d_in[0];   // (B,S,D) f32
    const int*   spans = (const int*)d_in[1];     // (B,N,2) i32
    float*       out   = (float*)d_out;           // (B,N,D) f32

    // Workspace: Q (16 MiB) + R (16 MiB); fully rewritten by K1 every launch
    // before K2 reads them -> poison-safe.
    float* Q = (float*)d_ws;
    float* R = Q + (size_t)PB * PS * PD;

    k_buildQR<<<dim3(PB * NRCH),   dim3(256), 0, stream>>>(seq, Q, R);
    k_gather <<<dim3(PB * PN / 4), dim3(256), 0, stream>>>(Q, R, spans, out);
}